// Round 1
// baseline (66738.776 us; speedup 1.0000x reference)
//
#include <hip/hip_runtime.h>
#include <hip/hip_bf16.h>

// dims fixed by the problem
#define S_LEN 512
#define B_SZ  32
#define H_DIM 512
#define KC    1024   // 2H

typedef __attribute__((ext_vector_type(8)))  short  short8;   // bf16x8
typedef __attribute__((ext_vector_type(4)))  float  f32x4;
typedef __attribute__((ext_vector_type(16))) float  f32x16;

static __device__ __forceinline__ unsigned short f2bf(float f){
  unsigned u = __float_as_uint(f);
  u += 0x7fffu + ((u >> 16) & 1u);          // RNE
  return (unsigned short)(u >> 16);
}
static __device__ __forceinline__ short8 cvt8(float4 a, float4 b){
  short8 r;
  r[0]=(short)f2bf(a.x); r[1]=(short)f2bf(a.y); r[2]=(short)f2bf(a.z); r[3]=(short)f2bf(a.w);
  r[4]=(short)f2bf(b.x); r[5]=(short)f2bf(b.y); r[6]=(short)f2bf(b.z); r[7]=(short)f2bf(b.w);
  return r;
}
static __device__ __forceinline__ float sigf(float x){ return 1.0f/(1.0f+__expf(-x)); }
static __device__ __forceinline__ float tanh_(float x){
  float e = __expf(2.0f*x);
  return (e-1.0f)/(e+1.0f);
}

// ------------------- gather / conversion kernels -------------------
__global__ __launch_bounds__(256) void k_gather_emb(const int* __restrict__ src,
    const float* __restrict__ Wemb, unsigned short* __restrict__ embB){
  int gid = blockIdx.x*256 + threadIdx.x;        // 1,048,576 threads total
  int row = gid >> 6;                            // token row r = s*B+b
  int k   = (gid & 63) * 8;
  int idx = src[row];
  const float* p = Wemb + (size_t)idx*H_DIM + k;
  float4 a = *(const float4*)p;
  float4 b = *(const float4*)(p+4);
  *(short8*)(embB + (size_t)gid*8) = cvt8(a,b);
}

// W_ih_r rows permuted to n=4h'+g so i/f/g/o are adjacent columns in the GEMM
__global__ __launch_bounds__(256) void k_perm_wr(const float* __restrict__ W,
    unsigned short* __restrict__ out){
  int gid = blockIdx.x*256 + threadIdx.x;        // 131072
  int n = gid >> 6;
  int k = (gid & 63)*8;
  int j = (n&3)*512 + (n>>2);
  const float* p = W + (size_t)j*512 + k;
  float4 a = *(const float4*)p;
  float4 b = *(const float4*)(p+4);
  *(short8*)(out + (size_t)gid*8) = cvt8(a,b);
}

__global__ __launch_bounds__(256) void k_perm_wihw(const float* __restrict__ W,
    unsigned short* __restrict__ out){
  int gid = blockIdx.x*256 + threadIdx.x;        // 262144
  int n = gid >> 7;
  int k = (gid & 127)*8;
  int j = (n&3)*512 + (n>>2);
  const float* p = W + (size_t)j*KC + k;
  float4 a = *(const float4*)p;
  float4 b = *(const float4*)(p+4);
  *(short8*)(out + (size_t)gid*8) = cvt8(a,b);
}

// WcT[k2][k1] = W_c[k1][k2] in bf16 (LDS tile transpose)
__global__ __launch_bounds__(256) void k_wcT(const float* __restrict__ Wc,
    unsigned short* __restrict__ out){
  __shared__ float tile[64][65];
  int bx = blockIdx.x & 15, by = blockIdx.x >> 4;
  int c0 = bx*64, r0 = by*64;
  int row = threadIdx.x >> 2;
  int cp  = (threadIdx.x & 3)*16;
  for (int i=0;i<16;i+=4){
    float4 v = *(const float4*)&Wc[(size_t)(r0+row)*KC + c0 + cp + i];
    tile[row][cp+i+0]=v.x; tile[row][cp+i+1]=v.y; tile[row][cp+i+2]=v.z; tile[row][cp+i+3]=v.w;
  }
  __syncthreads();
  short8 s0, s1;
  for(int i=0;i<8;++i){
    s0[i]=(short)f2bf(tile[cp+i][row]);
    s1[i]=(short)f2bf(tile[cp+8+i][row]);
  }
  unsigned short* op = out + (size_t)(c0+row)*KC + r0 + cp;
  *(short8*)op = s0; *(short8*)(op+8) = s1;
}

__global__ __launch_bounds__(256) void k_bias_r(const float* __restrict__ bi,
    const float* __restrict__ bh, float* __restrict__ out){
  int n = blockIdx.x*256 + threadIdx.x;  // 2048
  int j = (n&3)*512 + (n>>2);
  out[n] = bi[j] + bh[j];
}

// b_comb[n] = W_ih_w[j]·b_c + b_ih_w[j] + b_hh_w[j], rows permuted
__global__ __launch_bounds__(256) void k_bcomb(const float* __restrict__ Wihw,
    const float* __restrict__ bc, const float* __restrict__ bi,
    const float* __restrict__ bh, float* __restrict__ out){
  int n = blockIdx.x*256 + threadIdx.x;  // 2048
  int j = (n&3)*512 + (n>>2);
  const float* wp = Wihw + (size_t)j*KC;
  float s = 0.f;
  for (int l=0;l<KC;l+=4){
    float4 w = *(const float4*)&wp[l];
    float4 c = *(const float4*)&bc[l];
    s += w.x*c.x + w.y*c.y + w.z*c.z + w.w*c.w;
  }
  out[n] = s + bi[j] + bh[j];
}

// ------------------- bf16 MFMA GEMM  C = A·Bm^T  (A:[M][K], Bm:[N][K]) -----
// EPI=0: read-LSTM gate epilogue -> o_all f32 (cols are permuted gates 4h'+g)
// EPI=1: store bf16 (W_comb precompute)
template<int EPI>
__global__ __launch_bounds__(256) void gemm_k(const unsigned short* __restrict__ A,
    const unsigned short* __restrict__ Bm, int K, int bnCnt,
    const float* __restrict__ bias, float* __restrict__ outF,
    unsigned short* __restrict__ outB, int outStride){
  __shared__ __align__(16) char smem[66560];
  unsigned short* As = (unsigned short*)smem;        // [128][72]
  unsigned short* Bs = As + 128*72;                  // [128][72]
  float* epi = (float*)smem;                         // [4][64][65] (union)
  const int tid = threadIdx.x, lane = tid & 63, w = tid >> 6;
  const int wr = w >> 1, wc = w & 1;
  const int bm = blockIdx.x / bnCnt, bn = blockIdx.x % bnCnt;
  f32x4 acc[4][4] = {};
  const size_t Abase = (size_t)bm*128*K;
  const size_t Bbase = (size_t)bn*128*K;
  for (int k0 = 0; k0 < K; k0 += 64){
    __syncthreads();
    #pragma unroll
    for (int i = 0; i < 4; ++i){
      int idx = tid + i*256;
      int row = idx >> 3, cb = (idx & 7)*8;
      *(short8*)&As[row*72 + cb] = *(const short8*)&A[Abase + (size_t)row*K + k0 + cb];
      *(short8*)&Bs[row*72 + cb] = *(const short8*)&Bm[Bbase + (size_t)row*K + k0 + cb];
    }
    __syncthreads();
    #pragma unroll
    for (int kk = 0; kk < 64; kk += 32){
      short8 af[4], bf[4];
      #pragma unroll
      for (int i=0;i<4;++i) af[i] = *(short8*)&As[(wr*64 + i*16 + (lane&15))*72 + kk + (lane>>4)*8];
      #pragma unroll
      for (int j=0;j<4;++j) bf[j] = *(short8*)&Bs[(wc*64 + j*16 + (lane&15))*72 + kk + (lane>>4)*8];
      #pragma unroll
      for (int i=0;i<4;++i)
        #pragma unroll
        for (int j=0;j<4;++j)
          acc[i][j] = __builtin_amdgcn_mfma_f32_16x16x32_bf16(af[i], bf[j], acc[i][j], 0,0,0);
    }
  }
  if (EPI == 0){
    float bj[4];
    #pragma unroll
    for (int j=0;j<4;++j) bj[j] = bias[bn*128 + wc*64 + j*16 + (lane&15)];
    __syncthreads();
    float* ep = epi + w*(64*65);
    #pragma unroll
    for (int i=0;i<4;++i)
      #pragma unroll
      for (int j=0;j<4;++j)
        #pragma unroll
        for (int r=0;r<4;++r)
          ep[(i*16 + (lane>>4)*4 + r)*65 + j*16 + (lane&15)] = acc[i][j][r] + bj[j];
    __syncthreads();
    int rg = bm*128 + wr*64 + lane;     // token row
    #pragma unroll
    for (int q=0;q<16;++q){
      float gi = ep[lane*65 + q*4+0];
      float gg = ep[lane*65 + q*4+2];
      float go = ep[lane*65 + q*4+3];
      float c = sigf(gi)*tanh_(gg);     // f gate multiplies c0=0 -> unused
      float h = sigf(go)*tanh_(c);
      outF[(size_t)rg*H_DIM + bn*32 + wc*16 + q] = h;
    }
  } else {
    #pragma unroll
    for (int i=0;i<4;++i)
      #pragma unroll
      for (int j=0;j<4;++j)
        #pragma unroll
        for (int r=0;r<4;++r){
          int rg = bm*128 + wr*64 + i*16 + (lane>>4)*4 + r;
          int cg = bn*128 + wc*64 + j*16 + (lane&15);
          outB[(size_t)rg*outStride + cg] = f2bf(acc[i][j][r]);
        }
  }
}

// ------------------- persistent scan kernel -------------------
static __device__ __forceinline__ void gridBarrier(int* flags, int* go, int bid, int tid, int k){
  __syncthreads();
  __threadfence();
  if (tid == 0)
    __hip_atomic_store(&flags[bid], k, __ATOMIC_RELEASE, __HIP_MEMORY_SCOPE_AGENT);
  if (bid == 0){
    while (__hip_atomic_load(&flags[tid], __ATOMIC_ACQUIRE, __HIP_MEMORY_SCOPE_AGENT) < k){}
    __syncthreads();
    if (tid == 0)
      __hip_atomic_store(go, k, __ATOMIC_RELEASE, __HIP_MEMORY_SCOPE_AGENT);
  }
  if (tid == 0){
    while (__hip_atomic_load(go, __ATOMIC_ACQUIRE, __HIP_MEMORY_SCOPE_AGENT) < k){}
  }
  __syncthreads();
  __threadfence();
}

static __device__ __forceinline__ float blockReduce(float v, bool isMax, float* red4, int lane, int wv){
  #pragma unroll
  for (int m=32;m>0;m>>=1){
    float o = __shfl_xor(v, m);
    v = isMax ? fmaxf(v,o) : v+o;
  }
  __syncthreads();
  if (lane==0) red4[wv] = v;
  __syncthreads();
  float r0=red4[0], r1=red4[1], r2=red4[2], r3=red4[3];
  return isMax ? fmaxf(fmaxf(r0,r1),fmaxf(r2,r3)) : (r0+r1)+(r2+r3);
}

// block (b,chunk) owns M[b, chunk*64 .. +64, :] in LDS for the whole scan.
// Steady state per step t (one M sweep only):
//   score_t = (1-z_{t-1})*d + z_{t-1}*(h_{t-1}·o_t);  softmax -> z_t
//   sweep: row = (1-z_{t-1})row + z_{t-1}h_{t-1} (apply pending update),
//          m_t += z_t*row,  d_new = row·o_{t+1}
//   barrier; 64 blocks compute gates = x·W_comb^T via 32x32x16 MFMA (K split
//   over 4 waves), h_t/c_t epilogue; barrier.
__global__ __launch_bounds__(256,1) void scan_k(
    const int* __restrict__ src, const float* __restrict__ Wemb,
    const float* __restrict__ o_all, const unsigned short* __restrict__ Wcomb,
    const float* __restrict__ bcomb,
    float* __restrict__ dbuf, float* __restrict__ zbuf, float* __restrict__ mglob,
    float* __restrict__ hbuf, float* __restrict__ out,
    int* __restrict__ flags, int* __restrict__ go){
  __shared__ __align__(16) float Mrow[64*512];   // 128 KB
  __shared__ __align__(16) float scratch[4224];  // m-stage [4][512] / gates [4][32][33]
  __shared__ float red4[4];
  __shared__ float zt_own[64];
  __shared__ float zp_own[64];

  const int tid = threadIdx.x, lane = tid & 63, wv = tid >> 6;
  const int bid = blockIdx.x;
  const int b = bid >> 3, chunk = bid & 7;
  const int cbase = chunk*64;
  const int e8 = lane*8;
  int bk = 0;

  // ---- init: zero m parity0 + z parity0, gather M0 rows, prime d = M0·o_0 ----
  if (tid < 64){
    mglob[bid*64 + tid] = 0.f;
    zbuf[bid*64 + tid]  = 0.f;
  }
  {
    const float* o0 = o_all + (size_t)b*H_DIM;
    float4 os0 = *(const float4*)&o0[e8];
    float4 os1 = *(const float4*)&o0[e8+4];
    for (int rr=0; rr<16; ++rr){
      int lr = wv*16 + rr;
      int sg = cbase + lr;
      int idx = src[sg*B_SZ + b];
      const float* wp = Wemb + (size_t)idx*H_DIM + e8;
      float4 v0 = *(const float4*)wp;
      float4 v1 = *(const float4*)(wp+4);
      *(float4*)&Mrow[lr*512 + e8]     = v0;
      *(float4*)&Mrow[lr*512 + e8 + 4] = v1;
      float dd = v0.x*os0.x + v0.y*os0.y + v0.z*os0.z + v0.w*os0.w
               + v1.x*os1.x + v1.y*os1.y + v1.z*os1.z + v1.w*os1.w;
      #pragma unroll
      for (int m=32;m>0;m>>=1) dd += __shfl_xor(dd, m);
      if (lane==0) dbuf[(size_t)b*S_LEN + sg] = dd;   // parity 0
    }
  }
  gridBarrier(flags, go, bid, tid, ++bk);

  for (int t=0; t<S_LEN; ++t){
    const int pr = t & 1, pw = 1 - pr;
    const float* dR = dbuf + ((size_t)pr*B_SZ + b)*S_LEN;
    const float* zR = zbuf + ((size_t)pr*B_SZ + b)*S_LEN;
    float* zW = zbuf + ((size_t)pw*B_SZ + b)*S_LEN;
    float* dW = dbuf + ((size_t)pw*B_SZ + b)*S_LEN;
    const float* ot = o_all + ((size_t)t*B_SZ + b)*H_DIM;
    const float* hb = hbuf + (size_t)b*H_DIM;

    // ---- scores + softmax (z_prev==0 at t=0 so stale h is harmless) ----
    float hpart = hb[tid*2]*ot[tid*2] + hb[tid*2+1]*ot[tid*2+1];
    float hdot = blockReduce(hpart, false, red4, lane, wv);

    int s0 = tid, s1 = tid + 256;
    float zp0 = zR[s0], zp1 = zR[s1];
    float sc0 = (1.f - zp0)*dR[s0] + zp0*hdot;
    float sc1 = (1.f - zp1)*dR[s1] + zp1*hdot;
    float mx = blockReduce(fmaxf(sc0,sc1), true, red4, lane, wv);
    float ex0 = __expf(sc0 - mx), ex1 = __expf(sc1 - mx);
    float sm = blockReduce(ex0+ex1, false, red4, lane, wv);
    float inv = 1.f / sm;
    if ((unsigned)(s0 - cbase) < 64u){ zt_own[s0-cbase] = ex0*inv; zp_own[s0-cbase] = zp0; zW[s0] = ex0*inv; }
    if ((unsigned)(s1 - cbase) < 64u){ zt_own[s1-cbase] = ex1*inv; zp_own[s1-cbase] = zp1; zW[s1] = ex1*inv; }
    __syncthreads();

    // ---- single M sweep: pending update + m accum + next-d dot ----
    float4 hs0 = *(const float4*)&hb[e8];
    float4 hs1 = *(const float4*)&hb[e8+4];
    const bool hasNext = (t < S_LEN-1);
    const float* onx = o_all + ((size_t)(hasNext? t+1 : t)*B_SZ + b)*H_DIM;
    float4 os0 = *(const float4*)&onx[e8];
    float4 os1 = *(const float4*)&onx[e8+4];
    float m0=0,m1=0,m2=0,m3=0,m4=0,m5=0,m6=0,m7=0;
    for (int rr=0; rr<16; ++rr){
      int lr = wv*16 + rr;
      float zp = zp_own[lr], zt = zt_own[lr];
      float* mp = &Mrow[lr*512 + e8];
      float4 v0 = *(float4*)mp;
      float4 v1 = *(float4*)(mp+4);
      v0.x += zp*(hs0.x - v0.x); v0.y += zp*(hs0.y - v0.y);
      v0.z += zp*(hs0.z - v0.z); v0.w += zp*(hs0.w - v0.w);
      v1.x += zp*(hs1.x - v1.x); v1.y += zp*(hs1.y - v1.y);
      v1.z += zp*(hs1.z - v1.z); v1.w += zp*(hs1.w - v1.w);
      *(float4*)mp = v0; *(float4*)(mp+4) = v1;
      m0 += zt*v0.x; m1 += zt*v0.y; m2 += zt*v0.z; m3 += zt*v0.w;
      m4 += zt*v1.x; m5 += zt*v1.y; m6 += zt*v1.z; m7 += zt*v1.w;
      float dd = v0.x*os0.x + v0.y*os0.y + v0.z*os0.z + v0.w*os0.w
               + v1.x*os1.x + v1.y*os1.y + v1.z*os1.z + v1.w*os1.w;
      #pragma unroll
      for (int m=32;m>0;m>>=1) dd += __shfl_xor(dd, m);
      if (lane==0 && hasNext) dW[cbase + lr] = dd;
    }
    __syncthreads();
    *(float4*)&scratch[wv*512 + e8]     = make_float4(m0,m1,m2,m3);
    *(float4*)&scratch[wv*512 + e8 + 4] = make_float4(m4,m5,m6,m7);
    __syncthreads();
    {
      int i0 = tid*2;
      float a0 = scratch[i0]   + scratch[512+i0]   + scratch[1024+i0]   + scratch[1536+i0];
      float a1 = scratch[i0+1] + scratch[512+i0+1] + scratch[1024+i0+1] + scratch[1536+i0+1];
      float* mg = mglob + (size_t)(t&1)*B_SZ*H_DIM + (size_t)b*H_DIM;
      atomicAdd(&mg[i0],   a0);
      atomicAdd(&mg[i0+1], a1);
    }
    gridBarrier(flags, go, bid, tid, ++bk);

    // ---- phase B: gates = [o_t, m_t]·W_comb^T, h/c epilogue ----
    if (bid < 64){
      const int n0 = bid*32;                      // 32 gate cols per block
      const int rowb = lane & 31, kh = (lane>>5)*8;
      const float* xb = (wv < 2)
          ? (o_all + ((size_t)t*B_SZ + rowb)*H_DIM)
          : (mglob + (size_t)(t&1)*B_SZ*H_DIM + (size_t)rowb*H_DIM - 512);
      f32x16 acc = {0,0,0,0,0,0,0,0,0,0,0,0,0,0,0,0};
      #pragma unroll
      for (int kk2=0; kk2<16; ++kk2){
        int k = (wv*16 + kk2)*16 + kh;            // wave wv owns K slice
        const float* xp = xb + k;
        float4 xa = *(const float4*)xp;
        float4 xc = *(const float4*)(xp+4);
        short8 af = cvt8(xa, xc);
        short8 bf = *(const short8*)&Wcomb[(size_t)(n0 + rowb)*KC + k];
        acc = __builtin_amdgcn_mfma_f32_32x32x16_bf16(af, bf, acc, 0,0,0);
      }
      float* gw = scratch + wv*1056;              // [32][33] per wave
      #pragma unroll
      for (int r=0;r<16;++r){
        int row = (r&3) + 8*(r>>2) + 4*(lane>>5);
        gw[row*33 + (lane&31)] = acc[r];
      }
      __syncthreads();
      {
        int bb = tid & 31, hl = tid >> 5;         // 32 b × 8 h' = 256 outputs
        float g4[4];
        #pragma unroll
        for (int g=0; g<4; ++g){
          int c = hl*4 + g;
          g4[g] = scratch[bb*33 + c] + scratch[1056 + bb*33 + c]
                + scratch[2112 + bb*33 + c] + scratch[3168 + bb*33 + c]
                + bcomb[n0 + c];
        }
        float cc = sigf(g4[0])*tanh_(g4[2]);
        float hh = sigf(g4[3])*tanh_(cc);
        int hpos = bid*8 + hl;
        hbuf[(size_t)bb*H_DIM + hpos] = hh;
        out[((size_t)t*B_SZ + bb)*H_DIM + hpos] = hh;
        if (t == S_LEN-1){
          out[(size_t)S_LEN*B_SZ*H_DIM + (size_t)bb*H_DIM + hpos] = hh;
          out[(size_t)S_LEN*B_SZ*H_DIM + (size_t)B_SZ*H_DIM + (size_t)bb*H_DIM + hpos] = cc;
        }
      }
    } else if (bid < 96){
      // zero the other m parity for step t+1
      float* mg = mglob + (size_t)(1-(t&1))*B_SZ*H_DIM + (size_t)(bid-64)*512;
      mg[tid] = 0.f; mg[tid+256] = 0.f;
    }
    gridBarrier(flags, go, bid, tid, ++bk);
  }
}

// ------------------- host launch -------------------
extern "C" void kernel_launch(void* const* d_in, const int* in_sizes, int n_in,
                              void* d_out, int out_size, void* d_ws, size_t ws_size,
                              hipStream_t stream){
  const int*   src   = (const int*)  d_in[0];
  const float* Wemb  = (const float*)d_in[1];
  const float* Wihr  = (const float*)d_in[2];
  const float* bihr  = (const float*)d_in[3];
  const float* bhhr  = (const float*)d_in[4];
  const float* Wc    = (const float*)d_in[5];
  const float* bc    = (const float*)d_in[6];
  const float* Wihw  = (const float*)d_in[7];
  const float* bihw  = (const float*)d_in[8];
  const float* bhhw  = (const float*)d_in[9];
  float* out = (float*)d_out;

  char* ws = (char*)d_ws;
  size_t off = 0;
  auto alloc = [&](size_t bytes)->char*{
    char* p = ws + off; off += (bytes + 255) & ~(size_t)255; return p;
  };
  unsigned short* embB  = (unsigned short*)alloc((size_t)16384*512*2);
  float*          o_all = (float*)         alloc((size_t)16384*512*4);
  unsigned short* WrP   = (unsigned short*)alloc((size_t)2048*512*2);
  unsigned short* WiwP  = (unsigned short*)alloc((size_t)2048*1024*2);
  unsigned short* WcT   = (unsigned short*)alloc((size_t)1024*1024*2);
  unsigned short* Wcomb = (unsigned short*)alloc((size_t)2048*1024*2);
  float*          bperm = (float*)alloc(2048*4);
  float*          bcomb = (float*)alloc(2048*4);
  float*          dbuf  = (float*)alloc((size_t)2*32*512*4);
  float*          zbuf  = (float*)alloc((size_t)2*32*512*4);
  float*          mglob = (float*)alloc((size_t)2*32*512*4);
  float*          hbuf  = (float*)alloc((size_t)32*512*4);
  int*            flags = (int*)alloc(4096);
  int*            go    = flags + 256;

  hipMemsetAsync(flags, 0, 2048, stream);
  k_gather_emb<<<4096,256,0,stream>>>(src, Wemb, embB);
  k_perm_wr  <<<512, 256,0,stream>>>(Wihr, WrP);
  k_perm_wihw<<<1024,256,0,stream>>>(Wihw, WiwP);
  k_wcT      <<<256, 256,0,stream>>>(Wc, WcT);
  k_bias_r   <<<8,   256,0,stream>>>(bihr, bhhr, bperm);
  k_bcomb    <<<8,   256,0,stream>>>(Wihw, bc, bihw, bhhw, bcomb);
  // read-LSTM: gates[16384][2048] -> fused gate epilogue -> o_all
  gemm_k<0><<<2048,256,0,stream>>>(embB, WrP, 512, 16, bperm, o_all, nullptr, 0);
  // W_comb = (perm W_ih_w) @ W_c, bf16 out
  gemm_k<1><<<128,256,0,stream>>>(WiwP, WcT, 1024, 8, nullptr, nullptr, Wcomb, 1024);
  // persistent scan: 256 blocks = 256 CUs (128KB+ LDS forces 1 block/CU)
  scan_k<<<256,256,0,stream>>>(src, Wemb, o_all, Wcomb, bcomb,
                               dbuf, zbuf, mglob, hbuf, out, flags, go);
}

// Round 2
// 9115.686 us; speedup vs baseline: 7.3213x; 7.3213x over previous
//
#include <hip/hip_runtime.h>
#include <hip/hip_bf16.h>

// dims fixed by the problem
#define S_LEN 512
#define B_SZ  32
#define H_DIM 512
#define KC    1024   // 2H

typedef __attribute__((ext_vector_type(8)))  short  short8;   // bf16x8
typedef __attribute__((ext_vector_type(4)))  float  f32x4;
typedef __attribute__((ext_vector_type(16))) float  f32x16;

static __device__ __forceinline__ unsigned short f2bf(float f){
  unsigned u = __float_as_uint(f);
  u += 0x7fffu + ((u >> 16) & 1u);          // RNE
  return (unsigned short)(u >> 16);
}
static __device__ __forceinline__ short8 cvt8(float4 a, float4 b){
  short8 r;
  r[0]=(short)f2bf(a.x); r[1]=(short)f2bf(a.y); r[2]=(short)f2bf(a.z); r[3]=(short)f2bf(a.w);
  r[4]=(short)f2bf(b.x); r[5]=(short)f2bf(b.y); r[6]=(short)f2bf(b.z); r[7]=(short)f2bf(b.w);
  return r;
}
static __device__ __forceinline__ float sigf(float x){ return 1.0f/(1.0f+__expf(-x)); }
static __device__ __forceinline__ float tanh_(float x){
  float e = __expf(2.0f*x);
  return (e-1.0f)/(e+1.0f);
}

// ---- IF-coherent (sc-bypass) accessors: relaxed agent atomics, NO fences ----
static __device__ __forceinline__ void stf_cc(float* p, float v){
  __hip_atomic_store(p, v, __ATOMIC_RELAXED, __HIP_MEMORY_SCOPE_AGENT);
}
static __device__ __forceinline__ float ldf_cc(const float* p){
  return __hip_atomic_load((float*)p, __ATOMIC_RELAXED, __HIP_MEMORY_SCOPE_AGENT);
}
static __device__ __forceinline__ float2 ld2_cc(const float* p){
  unsigned long long u = __hip_atomic_load((unsigned long long*)p, __ATOMIC_RELAXED, __HIP_MEMORY_SCOPE_AGENT);
  float2 r; r.x = __uint_as_float((unsigned)u); r.y = __uint_as_float((unsigned)(u>>32));
  return r;
}
static __device__ __forceinline__ void st2_cc(float* p, float a, float b){
  unsigned long long u = (unsigned long long)__float_as_uint(a)
                       | ((unsigned long long)__float_as_uint(b)<<32);
  __hip_atomic_store((unsigned long long*)p, u, __ATOMIC_RELAXED, __HIP_MEMORY_SCOPE_AGENT);
}

// ------------------- gather / conversion kernels -------------------
__global__ __launch_bounds__(256) void k_gather_emb(const int* __restrict__ src,
    const float* __restrict__ Wemb, unsigned short* __restrict__ embB){
  int gid = blockIdx.x*256 + threadIdx.x;
  int row = gid >> 6;
  int k   = (gid & 63) * 8;
  int idx = src[row];
  const float* p = Wemb + (size_t)idx*H_DIM + k;
  float4 a = *(const float4*)p;
  float4 b = *(const float4*)(p+4);
  *(short8*)(embB + (size_t)gid*8) = cvt8(a,b);
}

__global__ __launch_bounds__(256) void k_perm_wr(const float* __restrict__ W,
    unsigned short* __restrict__ out){
  int gid = blockIdx.x*256 + threadIdx.x;
  int n = gid >> 6;
  int k = (gid & 63)*8;
  int j = (n&3)*512 + (n>>2);
  const float* p = W + (size_t)j*512 + k;
  float4 a = *(const float4*)p;
  float4 b = *(const float4*)(p+4);
  *(short8*)(out + (size_t)gid*8) = cvt8(a,b);
}

__global__ __launch_bounds__(256) void k_perm_wihw(const float* __restrict__ W,
    unsigned short* __restrict__ out){
  int gid = blockIdx.x*256 + threadIdx.x;
  int n = gid >> 7;
  int k = (gid & 127)*8;
  int j = (n&3)*512 + (n>>2);
  const float* p = W + (size_t)j*KC + k;
  float4 a = *(const float4*)p;
  float4 b = *(const float4*)(p+4);
  *(short8*)(out + (size_t)gid*8) = cvt8(a,b);
}

__global__ __launch_bounds__(256) void k_wcT(const float* __restrict__ Wc,
    unsigned short* __restrict__ out){
  __shared__ float tile[64][65];
  int bx = blockIdx.x & 15, by = blockIdx.x >> 4;
  int c0 = bx*64, r0 = by*64;
  int row = threadIdx.x >> 2;
  int cp  = (threadIdx.x & 3)*16;
  for (int i=0;i<16;i+=4){
    float4 v = *(const float4*)&Wc[(size_t)(r0+row)*KC + c0 + cp + i];
    tile[row][cp+i+0]=v.x; tile[row][cp+i+1]=v.y; tile[row][cp+i+2]=v.z; tile[row][cp+i+3]=v.w;
  }
  __syncthreads();
  short8 s0, s1;
  for(int i=0;i<8;++i){
    s0[i]=(short)f2bf(tile[cp+i][row]);
    s1[i]=(short)f2bf(tile[cp+8+i][row]);
  }
  unsigned short* op = out + (size_t)(c0+row)*KC + r0 + cp;
  *(short8*)op = s0; *(short8*)(op+8) = s1;
}

__global__ __launch_bounds__(256) void k_bias_r(const float* __restrict__ bi,
    const float* __restrict__ bh, float* __restrict__ out){
  int n = blockIdx.x*256 + threadIdx.x;
  int j = (n&3)*512 + (n>>2);
  out[n] = bi[j] + bh[j];
}

__global__ __launch_bounds__(256) void k_bcomb(const float* __restrict__ Wihw,
    const float* __restrict__ bc, const float* __restrict__ bi,
    const float* __restrict__ bh, float* __restrict__ out){
  int n = blockIdx.x*256 + threadIdx.x;
  int j = (n&3)*512 + (n>>2);
  const float* wp = Wihw + (size_t)j*KC;
  float s = 0.f;
  for (int l=0;l<KC;l+=4){
    float4 w = *(const float4*)&wp[l];
    float4 c = *(const float4*)&bc[l];
    s += w.x*c.x + w.y*c.y + w.z*c.z + w.w*c.w;
  }
  out[n] = s + bi[j] + bh[j];
}

// ------------------- bf16 MFMA GEMM  C = A·Bm^T -------------------
template<int EPI>
__global__ __launch_bounds__(256) void gemm_k(const unsigned short* __restrict__ A,
    const unsigned short* __restrict__ Bm, int K, int bnCnt,
    const float* __restrict__ bias, float* __restrict__ outF,
    unsigned short* __restrict__ outB, int outStride){
  __shared__ __align__(16) char smem[66560];
  unsigned short* As = (unsigned short*)smem;
  unsigned short* Bs = As + 128*72;
  float* epi = (float*)smem;
  const int tid = threadIdx.x, lane = tid & 63, w = tid >> 6;
  const int wr = w >> 1, wc = w & 1;
  const int bm = blockIdx.x / bnCnt, bn = blockIdx.x % bnCnt;
  f32x4 acc[4][4] = {};
  const size_t Abase = (size_t)bm*128*K;
  const size_t Bbase = (size_t)bn*128*K;
  for (int k0 = 0; k0 < K; k0 += 64){
    __syncthreads();
    #pragma unroll
    for (int i = 0; i < 4; ++i){
      int idx = tid + i*256;
      int row = idx >> 3, cb = (idx & 7)*8;
      *(short8*)&As[row*72 + cb] = *(const short8*)&A[Abase + (size_t)row*K + k0 + cb];
      *(short8*)&Bs[row*72 + cb] = *(const short8*)&Bm[Bbase + (size_t)row*K + k0 + cb];
    }
    __syncthreads();
    #pragma unroll
    for (int kk = 0; kk < 64; kk += 32){
      short8 af[4], bf[4];
      #pragma unroll
      for (int i=0;i<4;++i) af[i] = *(short8*)&As[(wr*64 + i*16 + (lane&15))*72 + kk + (lane>>4)*8];
      #pragma unroll
      for (int j=0;j<4;++j) bf[j] = *(short8*)&Bs[(wc*64 + j*16 + (lane&15))*72 + kk + (lane>>4)*8];
      #pragma unroll
      for (int i=0;i<4;++i)
        #pragma unroll
        for (int j=0;j<4;++j)
          acc[i][j] = __builtin_amdgcn_mfma_f32_16x16x32_bf16(af[i], bf[j], acc[i][j], 0,0,0);
    }
  }
  if (EPI == 0){
    float bj[4];
    #pragma unroll
    for (int j=0;j<4;++j) bj[j] = bias[bn*128 + wc*64 + j*16 + (lane&15)];
    __syncthreads();
    float* ep = epi + w*(64*65);
    #pragma unroll
    for (int i=0;i<4;++i)
      #pragma unroll
      for (int j=0;j<4;++j)
        #pragma unroll
        for (int r=0;r<4;++r)
          ep[(i*16 + (lane>>4)*4 + r)*65 + j*16 + (lane&15)] = acc[i][j][r] + bj[j];
    __syncthreads();
    int rg = bm*128 + wr*64 + lane;
    #pragma unroll
    for (int q=0;q<16;++q){
      float gi = ep[lane*65 + q*4+0];
      float gg = ep[lane*65 + q*4+2];
      float go = ep[lane*65 + q*4+3];
      float c = sigf(gi)*tanh_(gg);
      float h = sigf(go)*tanh_(c);
      outF[(size_t)rg*H_DIM + bn*32 + wc*16 + q] = h;
    }
  } else {
    #pragma unroll
    for (int i=0;i<4;++i)
      #pragma unroll
      for (int j=0;j<4;++j)
        #pragma unroll
        for (int r=0;r<4;++r){
          int rg = bm*128 + wr*64 + i*16 + (lane>>4)*4 + r;
          int cg = bn*128 + wc*64 + j*16 + (lane&15);
          outB[(size_t)rg*outStride + cg] = f2bf(acc[i][j][r]);
        }
  }
}

// ------------------- persistent scan kernel -------------------
// Fence-free grid barrier: all cross-block data moves via sc-bypass (agent
// relaxed atomic) accesses that are coherent at the IF point; __syncthreads
// drains vmcnt before the flag store, so no wbl2/inv cache maintenance.
static __device__ __forceinline__ void gridBarrier(int* flags, int* go, int bid, int tid, int k){
  __syncthreads();                                   // drains vmcnt/lgkmcnt
  asm volatile("" ::: "memory");
  if (tid == 0)
    __hip_atomic_store(&flags[bid], k, __ATOMIC_RELAXED, __HIP_MEMORY_SCOPE_AGENT);
  if (bid == 0){
    while (__hip_atomic_load(&flags[tid], __ATOMIC_RELAXED, __HIP_MEMORY_SCOPE_AGENT) < k)
      __builtin_amdgcn_s_sleep(1);
    __syncthreads();
    if (tid == 0)
      __hip_atomic_store(go, k, __ATOMIC_RELAXED, __HIP_MEMORY_SCOPE_AGENT);
  } else if (tid == 0){
    while (__hip_atomic_load(go, __ATOMIC_RELAXED, __HIP_MEMORY_SCOPE_AGENT) < k)
      __builtin_amdgcn_s_sleep(1);
  }
  __syncthreads();
  asm volatile("" ::: "memory");
}

static __device__ __forceinline__ float blockReduce(float v, bool isMax, float* red4, int lane, int wv){
  #pragma unroll
  for (int m=32;m>0;m>>=1){
    float o = __shfl_xor(v, m);
    v = isMax ? fmaxf(v,o) : v+o;
  }
  __syncthreads();
  if (lane==0) red4[wv] = v;
  __syncthreads();
  float r0=red4[0], r1=red4[1], r2=red4[2], r3=red4[3];
  return isMax ? fmaxf(fmaxf(r0,r1),fmaxf(r2,r3)) : (r0+r1)+(r2+r3);
}

// b = bid&31, chunk = bid>>5  -> a batch's 8 chunk-blocks share an XCD (bid%8).
__global__ __launch_bounds__(256,1) void scan_k(
    const int* __restrict__ src, const float* __restrict__ Wemb,
    const float* __restrict__ o_all, const unsigned short* __restrict__ Wcomb,
    const float* __restrict__ bcomb,
    float* __restrict__ dbuf, float* __restrict__ zbuf, float* __restrict__ mglob,
    float* __restrict__ hbuf, float* __restrict__ out,
    int* __restrict__ flags, int* __restrict__ go){
  __shared__ __align__(16) float Mrow[64*512];   // 128 KB
  __shared__ __align__(16) float scratch[4224];
  __shared__ float red4[4];
  __shared__ float zt_own[64];
  __shared__ float zp_own[64];

  const int tid = threadIdx.x, lane = tid & 63, wv = tid >> 6;
  const int bid = blockIdx.x;
  const int b = bid & 31, chunk = bid >> 5;
  const int cbase = chunk*64;
  const int cA = lane*4, cB = 256 + lane*4;      // lane-contiguous: no LDS bank conflict
  int bk = 0;

  // ---- init: zero m/z parity0, gather M0 rows, prime d = M0·o_0 ----
  if (tid < 64){
    stf_cc(&mglob[bid*64 + tid], 0.f);
    stf_cc(&zbuf[bid*64 + tid],  0.f);
  }
  {
    const float* o0 = o_all + (size_t)b*H_DIM;
    float4 osA = *(const float4*)&o0[cA];
    float4 osB = *(const float4*)&o0[cB];
    for (int rr=0; rr<16; ++rr){
      int lr = wv*16 + rr;
      int sg = cbase + lr;
      int idx = src[sg*B_SZ + b];
      const float* wp = Wemb + (size_t)idx*H_DIM;
      float4 v0 = *(const float4*)&wp[cA];
      float4 v1 = *(const float4*)&wp[cB];
      *(float4*)&Mrow[lr*512 + cA] = v0;
      *(float4*)&Mrow[lr*512 + cB] = v1;
      float dd = v0.x*osA.x + v0.y*osA.y + v0.z*osA.z + v0.w*osA.w
               + v1.x*osB.x + v1.y*osB.y + v1.z*osB.z + v1.w*osB.w;
      #pragma unroll
      for (int m=32;m>0;m>>=1) dd += __shfl_xor(dd, m);
      if (lane==0) stf_cc(&dbuf[(size_t)b*S_LEN + sg], dd);   // parity 0
    }
  }
  gridBarrier(flags, go, bid, tid, ++bk);

  for (int t=0; t<S_LEN; ++t){
    const int pr = t & 1, pw = 1 - pr;
    const float* dR = dbuf + ((size_t)pr*B_SZ + b)*S_LEN;
    const float* zR = zbuf + ((size_t)pr*B_SZ + b)*S_LEN;
    float* zW = zbuf + ((size_t)pw*B_SZ + b)*S_LEN;
    float* dW = dbuf + ((size_t)pw*B_SZ + b)*S_LEN;
    const float* ot = o_all + ((size_t)t*B_SZ + b)*H_DIM;
    const float* hb = hbuf + (size_t)b*H_DIM;

    // ---- scores + softmax (z_prev==0 at t=0 so stale h is harmless) ----
    float2 hp = ld2_cc(&hb[tid*2]);
    float hpart = hp.x*ot[tid*2] + hp.y*ot[tid*2+1];
    float hdot = blockReduce(hpart, false, red4, lane, wv);

    int s0 = tid, s1 = tid + 256;
    float zp0 = ldf_cc(&zR[s0]), zp1 = ldf_cc(&zR[s1]);
    float sc0 = (1.f - zp0)*ldf_cc(&dR[s0]) + zp0*hdot;
    float sc1 = (1.f - zp1)*ldf_cc(&dR[s1]) + zp1*hdot;
    float mx = blockReduce(fmaxf(sc0,sc1), true, red4, lane, wv);
    float ex0 = __expf(sc0 - mx), ex1 = __expf(sc1 - mx);
    float sm = blockReduce(ex0+ex1, false, red4, lane, wv);
    float inv = 1.f / sm;
    if ((unsigned)(s0 - cbase) < 64u){ zt_own[s0-cbase] = ex0*inv; zp_own[s0-cbase] = zp0; stf_cc(&zW[s0], ex0*inv); }
    if ((unsigned)(s1 - cbase) < 64u){ zt_own[s1-cbase] = ex1*inv; zp_own[s1-cbase] = zp1; stf_cc(&zW[s1], ex1*inv); }
    __syncthreads();

    // ---- single M sweep: pending update + m accum + next-d dot ----
    float2 h0 = ld2_cc(&hb[cA]),   h1 = ld2_cc(&hb[cA+2]);
    float2 h2 = ld2_cc(&hb[cB]),   h3 = ld2_cc(&hb[cB+2]);
    float4 hsA = make_float4(h0.x,h0.y,h1.x,h1.y);
    float4 hsB = make_float4(h2.x,h2.y,h3.x,h3.y);
    const bool hasNext = (t < S_LEN-1);
    const float* onx = o_all + ((size_t)(hasNext? t+1 : t)*B_SZ + b)*H_DIM;
    float4 osA = *(const float4*)&onx[cA];
    float4 osB = *(const float4*)&onx[cB];
    float m0=0,m1=0,m2=0,m3=0,m4=0,m5=0,m6=0,m7=0;
    for (int rr=0; rr<16; ++rr){
      int lr = wv*16 + rr;
      float zp = zp_own[lr], zt = zt_own[lr];
      float* mpA = &Mrow[lr*512 + cA];
      float* mpB = &Mrow[lr*512 + cB];
      float4 v0 = *(float4*)mpA;
      float4 v1 = *(float4*)mpB;
      v0.x += zp*(hsA.x - v0.x); v0.y += zp*(hsA.y - v0.y);
      v0.z += zp*(hsA.z - v0.z); v0.w += zp*(hsA.w - v0.w);
      v1.x += zp*(hsB.x - v1.x); v1.y += zp*(hsB.y - v1.y);
      v1.z += zp*(hsB.z - v1.z); v1.w += zp*(hsB.w - v1.w);
      *(float4*)mpA = v0; *(float4*)mpB = v1;
      m0 += zt*v0.x; m1 += zt*v0.y; m2 += zt*v0.z; m3 += zt*v0.w;
      m4 += zt*v1.x; m5 += zt*v1.y; m6 += zt*v1.z; m7 += zt*v1.w;
      float dd = v0.x*osA.x + v0.y*osA.y + v0.z*osA.z + v0.w*osA.w
               + v1.x*osB.x + v1.y*osB.y + v1.z*osB.z + v1.w*osB.w;
      #pragma unroll
      for (int m=32;m>0;m>>=1) dd += __shfl_xor(dd, m);
      if (lane==0 && hasNext) stf_cc(&dW[cbase + lr], dd);
    }
    __syncthreads();
    *(float4*)&scratch[wv*512 + cA] = make_float4(m0,m1,m2,m3);
    *(float4*)&scratch[wv*512 + cB] = make_float4(m4,m5,m6,m7);
    __syncthreads();
    {
      int i0 = tid*2;
      float a0 = scratch[i0]   + scratch[512+i0]   + scratch[1024+i0]   + scratch[1536+i0];
      float a1 = scratch[i0+1] + scratch[512+i0+1] + scratch[1024+i0+1] + scratch[1536+i0+1];
      float* mg = mglob + (size_t)(t&1)*B_SZ*H_DIM + (size_t)b*H_DIM;
      atomicAdd(&mg[i0],   a0);     // device-scope fp32 atomic: IF-coherent
      atomicAdd(&mg[i0+1], a1);
    }
    gridBarrier(flags, go, bid, tid, ++bk);

    // ---- phase B (blocks 128..191): gates = [o_t, m_t]·W_comb^T ----
    if (bid >= 128 && bid < 192){
      const int nb = bid - 128;
      const int n0 = nb*32;
      const int rowb = lane & 31, kh = (lane>>5)*8;
      const float* mgB = mglob + (size_t)(t&1)*B_SZ*H_DIM + (size_t)rowb*H_DIM;
      const float* oB  = o_all + ((size_t)t*B_SZ + rowb)*H_DIM;
      f32x16 acc = {0,0,0,0,0,0,0,0,0,0,0,0,0,0,0,0};
      #pragma unroll
      for (int kk2=0; kk2<16; ++kk2){
        int k = (wv*16 + kk2)*16 + kh;
        float4 xa, xc;
        if (wv < 2){
          const float* xp = oB + k;
          xa = *(const float4*)xp; xc = *(const float4*)(xp+4);
        } else {
          const float* xp = mgB + (k - 512);
          float2 p0 = ld2_cc(xp),   p1 = ld2_cc(xp+2);
          float2 p2 = ld2_cc(xp+4), p3 = ld2_cc(xp+6);
          xa = make_float4(p0.x,p0.y,p1.x,p1.y);
          xc = make_float4(p2.x,p2.y,p3.x,p3.y);
        }
        short8 af = cvt8(xa, xc);
        short8 bf = *(const short8*)&Wcomb[(size_t)(n0 + rowb)*KC + k];
        acc = __builtin_amdgcn_mfma_f32_32x32x16_bf16(af, bf, acc, 0,0,0);
      }
      float* gw = scratch + wv*1056;
      #pragma unroll
      for (int r=0;r<16;++r){
        int row = (r&3) + 8*(r>>2) + 4*(lane>>5);
        gw[row*33 + (lane&31)] = acc[r];
      }
      __syncthreads();
      {
        int bb = tid & 31, hl = tid >> 5;
        float g4[4];
        #pragma unroll
        for (int g=0; g<4; ++g){
          int c = hl*4 + g;
          g4[g] = scratch[bb*33 + c] + scratch[1056 + bb*33 + c]
                + scratch[2112 + bb*33 + c] + scratch[3168 + bb*33 + c]
                + bcomb[n0 + c];
        }
        float cc = sigf(g4[0])*tanh_(g4[2]);
        float hh = sigf(g4[3])*tanh_(cc);
        int hpos = nb*8 + hl;
        stf_cc(&hbuf[(size_t)bb*H_DIM + hpos], hh);
        out[((size_t)t*B_SZ + bb)*H_DIM + hpos] = hh;   // out: host-read only
        if (t == S_LEN-1){
          out[(size_t)S_LEN*B_SZ*H_DIM + (size_t)bb*H_DIM + hpos] = hh;
          out[(size_t)S_LEN*B_SZ*H_DIM + (size_t)B_SZ*H_DIM + (size_t)bb*H_DIM + hpos] = cc;
        }
      }
    } else if (bid >= 192 && bid < 224){
      // zero the other m parity for step t+1
      float* mg = mglob + (size_t)(1-(t&1))*B_SZ*H_DIM + (size_t)(bid-192)*512;
      stf_cc(&mg[tid], 0.f); stf_cc(&mg[tid+256], 0.f);
    }
    gridBarrier(flags, go, bid, tid, ++bk);
  }
}

// ------------------- host launch -------------------
extern "C" void kernel_launch(void* const* d_in, const int* in_sizes, int n_in,
                              void* d_out, int out_size, void* d_ws, size_t ws_size,
                              hipStream_t stream){
  const int*   src   = (const int*)  d_in[0];
  const float* Wemb  = (const float*)d_in[1];
  const float* Wihr  = (const float*)d_in[2];
  const float* bihr  = (const float*)d_in[3];
  const float* bhhr  = (const float*)d_in[4];
  const float* Wc    = (const float*)d_in[5];
  const float* bc    = (const float*)d_in[6];
  const float* Wihw  = (const float*)d_in[7];
  const float* bihw  = (const float*)d_in[8];
  const float* bhhw  = (const float*)d_in[9];
  float* out = (float*)d_out;

  char* ws = (char*)d_ws;
  size_t off = 0;
  auto alloc = [&](size_t bytes)->char*{
    char* p = ws + off; off += (bytes + 255) & ~(size_t)255; return p;
  };
  unsigned short* embB  = (unsigned short*)alloc((size_t)16384*512*2);
  float*          o_all = (float*)         alloc((size_t)16384*512*4);
  unsigned short* WrP   = (unsigned short*)alloc((size_t)2048*512*2);
  unsigned short* WiwP  = (unsigned short*)alloc((size_t)2048*1024*2);
  unsigned short* WcT   = (unsigned short*)alloc((size_t)1024*1024*2);
  unsigned short* Wcomb = (unsigned short*)alloc((size_t)2048*1024*2);
  float*          bperm = (float*)alloc(2048*4);
  float*          bcomb = (float*)alloc(2048*4);
  float*          dbuf  = (float*)alloc((size_t)2*32*512*4);
  float*          zbuf  = (float*)alloc((size_t)2*32*512*4);
  float*          mglob = (float*)alloc((size_t)2*32*512*4);
  float*          hbuf  = (float*)alloc((size_t)32*512*4);
  int*            flags = (int*)alloc(4096);
  int*            go    = flags + 256;

  hipMemsetAsync(flags, 0, 2048, stream);
  k_gather_emb<<<4096,256,0,stream>>>(src, Wemb, embB);
  k_perm_wr  <<<512, 256,0,stream>>>(Wihr, WrP);
  k_perm_wihw<<<1024,256,0,stream>>>(Wihw, WiwP);
  k_wcT      <<<256, 256,0,stream>>>(Wc, WcT);
  k_bias_r   <<<8,   256,0,stream>>>(bihr, bhhr, bperm);
  k_bcomb    <<<8,   256,0,stream>>>(Wihw, bc, bihw, bhhw, bcomb);
  gemm_k<0><<<2048,256,0,stream>>>(embB, WrP, 512, 16, bperm, o_all, nullptr, 0);
  gemm_k<1><<<128,256,0,stream>>>(WiwP, WcT, 1024, 8, nullptr, nullptr, Wcomb, 1024);
  scan_k<<<256,256,0,stream>>>(src, Wemb, o_all, Wcomb, bcomb,
                               dbuf, zbuf, mglob, hbuf, out, flags, go);
}